// Round 3
// baseline (400.215 us; speedup 1.0000x reference)
//
#include <hip/hip_runtime.h>
#include <hip/hip_bf16.h>
#include <hip/hip_fp16.h>

#define BATCH 4
#define NQ 4096
#define NK 4096
#define DIM 64

typedef __attribute__((ext_vector_type(8))) short bf16x8;
typedef __attribute__((ext_vector_type(4))) float f32x4;

// round-to-nearest-even f32 -> bf16
__device__ __forceinline__ unsigned short f2bf(float f) {
  union { float f; unsigned u; } v; v.f = f;
  return (unsigned short)((v.u + 0x7FFF + ((v.u >> 16) & 1)) >> 16);
}

// Stage a ROWS x 64 f32 row-major tile (contiguous) into LDS as bf16 with
// 16B-slot XOR swizzle (slot ^= row&7, row stride 128B), and compute per-row
// sum of squares in f32 from the original global data.
template<int ROWS>
__device__ __forceinline__ void stage_tile(const float* __restrict__ g, char* lds,
                                           float* sq, int tid) {
  constexpr int NV = ROWS * 16;  // number of float4 chunks
  #pragma unroll
  for (int i = 0; i < NV / 256; ++i) {
    const int idx = i * 256 + tid;
    const float4 v = reinterpret_cast<const float4*>(g)[idx];
    const int f = idx * 4;
    const int row = f >> 6, col = f & 63;
    uint2 pk;
    pk.x = (unsigned)f2bf(v.x) | ((unsigned)f2bf(v.y) << 16);
    pk.y = (unsigned)f2bf(v.z) | ((unsigned)f2bf(v.w) << 16);
    const int byte = row * 128 + ((((col >> 3) ^ (row & 7)) << 4)) + ((col >> 2) & 1) * 8;
    *reinterpret_cast<uint2*>(lds + byte) = pk;
  }
  if (tid < ROWS) {
    const float4* rp = reinterpret_cast<const float4*>(g + tid * DIM);
    float s = 0.f;
    #pragma unroll
    for (int j = 0; j < 16; ++j) {
      const float4 v = rp[j];
      s += v.x * v.x + v.y * v.y + v.z * v.z + v.w * v.w;
    }
    sq[tid] = s;
  }
}

// Load one 16x32 MFMA operand fragment (8 bf16 per lane) from swizzled LDS.
__device__ __forceinline__ bf16x8 frag_load(const char* lds, int row, int ks, int lane) {
  return *reinterpret_cast<const bf16x8*>(
      lds + row * 128 + (((ks * 4 + (lane >> 4)) ^ (row & 7)) << 4));
}

// Single compute pass: e = exp(-sqrt(max(q2+k2-2qk,0))/8), written UNNORMALIZED
// (f16 to ws if F16WS, else f32 to out), plus per-row partial sums.
// Swapped MFMA (mfma(K,Q)): acc[i] = S[qrow = w*16+(lane&15)]
//                                     [kcol = c*16 + (lane>>4)*4 + i]
// -> each lane owns 4 consecutive output cols of one row: packed stores.
// grid (NK/256, NQ/64, BATCH), block 256.
template<bool F16WS>
__global__ __launch_bounds__(256) void k_score(
    const float* __restrict__ Qg, const float* __restrict__ Kg,
    void* __restrict__ score, float* __restrict__ partials) {
  __shared__ char Qlds[64 * 128];
  __shared__ char Klds[256 * 128];
  __shared__ float q2[64];
  __shared__ float k2[256];
  const int tid = threadIdx.x;
  const int bcol = blockIdx.x * 256;
  const int brow = blockIdx.y * 64;
  const int b = blockIdx.z;
  const float* Qb = Qg + ((size_t)b * NQ + brow) * DIM;
  const float* Kb = Kg + ((size_t)b * NK + bcol) * DIM;

  stage_tile<64>(Qb, Qlds, q2, tid);
  stage_tile<256>(Kb, Klds, k2, tid);
  __syncthreads();

  const int lane = tid & 63, w = tid >> 6;
  const int qrow = w * 16 + (lane & 15);
  const bf16x8 qf0 = frag_load(Qlds, qrow, 0, lane);
  const bf16x8 qf1 = frag_load(Qlds, qrow, 1, lane);
  const float q2r = q2[qrow];
  const int g = lane >> 4;

  float rowsum = 0.f;
  const size_t rbase = ((size_t)b * NQ + brow + qrow) * NK + bcol + g * 4;

  #pragma unroll
  for (int c = 0; c < 16; ++c) {
    const int krow = c * 16 + (lane & 15);
    const bf16x8 kf0 = frag_load(Klds, krow, 0, lane);
    const bf16x8 kf1 = frag_load(Klds, krow, 1, lane);
    f32x4 acc = {0.f, 0.f, 0.f, 0.f};
    acc = __builtin_amdgcn_mfma_f32_16x16x32_bf16(kf0, qf0, acc, 0, 0, 0);
    acc = __builtin_amdgcn_mfma_f32_16x16x32_bf16(kf1, qf1, acc, 0, 0, 0);
    const float4 k2v = *reinterpret_cast<const float4*>(k2 + c * 16 + g * 4);

    float e[4];
    const float k2a[4] = {k2v.x, k2v.y, k2v.z, k2v.w};
    #pragma unroll
    for (int i = 0; i < 4; ++i) {
      const float d2 = fmaxf(q2r + k2a[i] - 2.f * acc[i], 0.f);
      e[i] = __expf(-0.125f * sqrtf(d2));
    }
    if (F16WS) {
      const __half h0 = __float2half_rn(e[0]), h1 = __float2half_rn(e[1]);
      const __half h2 = __float2half_rn(e[2]), h3 = __float2half_rn(e[3]);
      // sum the ROUNDED values so normalization matches what pass 2 reads
      rowsum += __half2float(h0) + __half2float(h1) +
                __half2float(h2) + __half2float(h3);
      uint2 pk;
      pk.x = (unsigned)__half_as_ushort(h0) | ((unsigned)__half_as_ushort(h1) << 16);
      pk.y = (unsigned)__half_as_ushort(h2) | ((unsigned)__half_as_ushort(h3) << 16);
      *reinterpret_cast<uint2*>((__half*)score + rbase + c * 16) = pk;
    } else {
      rowsum += e[0] + e[1] + e[2] + e[3];
      float4 st = {e[0], e[1], e[2], e[3]};
      *reinterpret_cast<float4*>((float*)score + rbase + c * 16) = st;
    }
  }

  // lanes {l, l^16, l^32, l^48} share a row -> reduce over bits 4,5
  rowsum += __shfl_xor(rowsum, 16, 64);
  rowsum += __shfl_xor(rowsum, 32, 64);
  if (lane < 16)
    partials[((size_t)blockIdx.x * BATCH + b) * NQ + brow + w * 16 + lane] = rowsum;
}

// Collapse 16 partials per row -> inv = 1/rowsum.  grid 64 x 256.
__global__ __launch_bounds__(256) void k_inv(
    const float* __restrict__ partials, float* __restrict__ inv) {
  const int idx = blockIdx.x * 256 + threadIdx.x;  // b*NQ + row, 0..16383
  float s = 0.f;
  #pragma unroll
  for (int p = 0; p < 16; ++p) s += partials[(size_t)p * (BATCH * NQ) + idx];
  inv[idx] = 1.f / s;
}

// out[r][c] = f32(score_f16[r][c]) * inv[r].  8 elems/thread, grid-stride.
__global__ __launch_bounds__(256) void k_scale_f16(
    const __half* __restrict__ sc, const float* __restrict__ inv,
    float* __restrict__ out) {
  const size_t nchunk = (size_t)BATCH * NQ * NK / 8;
  const size_t stride = (size_t)gridDim.x * blockDim.x;
  for (size_t c = (size_t)blockIdx.x * blockDim.x + threadIdx.x; c < nchunk; c += stride) {
    const int rg = (int)(c >> 9);  // 512 chunks per row
    const float iv = inv[rg];
    union { uint4 u; __half h[8]; } U;
    U.u = reinterpret_cast<const uint4*>(sc)[c];
    float4 a, bq;
    a.x = __half2float(U.h[0]) * iv; a.y = __half2float(U.h[1]) * iv;
    a.z = __half2float(U.h[2]) * iv; a.w = __half2float(U.h[3]) * iv;
    bq.x = __half2float(U.h[4]) * iv; bq.y = __half2float(U.h[5]) * iv;
    bq.z = __half2float(U.h[6]) * iv; bq.w = __half2float(U.h[7]) * iv;
    float4* op = reinterpret_cast<float4*>(out) + 2 * c;
    op[0] = a; op[1] = bq;
  }
}

// Fallback: in-place scale of f32 scores already in out.  4 elems/thread.
__global__ __launch_bounds__(256) void k_scale_f32(
    const float* __restrict__ inv, float* __restrict__ out) {
  const size_t nchunk = (size_t)BATCH * NQ * NK / 4;
  const size_t stride = (size_t)gridDim.x * blockDim.x;
  for (size_t c = (size_t)blockIdx.x * blockDim.x + threadIdx.x; c < nchunk; c += stride) {
    const int rg = (int)(c >> 10);  // 1024 chunks per row
    const float iv = inv[rg];
    float4 v = reinterpret_cast<float4*>(out)[c];
    v.x *= iv; v.y *= iv; v.z *= iv; v.w *= iv;
    reinterpret_cast<float4*>(out)[c] = v;
  }
}

extern "C" void kernel_launch(void* const* d_in, const int* in_sizes, int n_in,
                              void* d_out, int out_size, void* d_ws, size_t ws_size,
                              hipStream_t stream) {
  const float* Q = (const float*)d_in[0];
  const float* K = (const float*)d_in[1];
  float* out = (float*)d_out;

  const size_t P_BYTES = (size_t)16 * BATCH * NQ * 4;   // 1 MB partials
  const size_t I_BYTES = (size_t)BATCH * NQ * 4;        // 64 KB inv
  const size_t S_BYTES = (size_t)BATCH * NQ * NK * 2;   // 134 MB f16 scores
  float* partials = (float*)d_ws;
  float* inv = (float*)((char*)d_ws + P_BYTES);
  __half* sc = (__half*)((char*)d_ws + P_BYTES + I_BYTES);

  if (ws_size >= P_BYTES + I_BYTES + S_BYTES) {
    k_score<true><<<dim3(NK / 256, NQ / 64, BATCH), dim3(256), 0, stream>>>(
        Q, K, (void*)sc, partials);
    k_inv<<<dim3(BATCH * NQ / 256), dim3(256), 0, stream>>>(partials, inv);
    k_scale_f16<<<dim3(2048), dim3(256), 0, stream>>>(sc, inv, out);
  } else {
    k_score<false><<<dim3(NK / 256, NQ / 64, BATCH), dim3(256), 0, stream>>>(
        Q, K, (void*)out, partials);
    k_inv<<<dim3(BATCH * NQ / 256), dim3(256), 0, stream>>>(partials, inv);
    k_scale_f32<<<dim3(2048), dim3(256), 0, stream>>>(inv, out);
  }
}

// Round 4
// 369.775 us; speedup vs baseline: 1.0823x; 1.0823x over previous
//
#include <hip/hip_runtime.h>
#include <hip/hip_bf16.h>

#define BATCH 4
#define NQ 4096
#define NK 4096
#define DIM 64

typedef __attribute__((ext_vector_type(8))) short bf16x8;
typedef __attribute__((ext_vector_type(4))) float f32x4;

// round-to-nearest-even f32 -> bf16
__device__ __forceinline__ unsigned short f2bf(float f) {
  union { float f; unsigned u; } v; v.f = f;
  return (unsigned short)((v.u + 0x7FFF + ((v.u >> 16) & 1)) >> 16);
}

// Stage a ROWS x 64 f32 row-major tile (contiguous) into LDS as bf16 with
// 16B-slot XOR swizzle (slot ^= row&7, row stride 128B), and compute per-row
// sum of squares in f32 from the original global data.
template<int ROWS>
__device__ __forceinline__ void stage_tile(const float* __restrict__ g, char* lds,
                                           float* sq, int tid) {
  constexpr int NV = ROWS * 16;  // number of float4 chunks
  #pragma unroll
  for (int i = 0; i < NV / 256; ++i) {
    const int idx = i * 256 + tid;
    const float4 v = reinterpret_cast<const float4*>(g)[idx];
    const int f = idx * 4;
    const int row = f >> 6, col = f & 63;
    uint2 pk;
    pk.x = (unsigned)f2bf(v.x) | ((unsigned)f2bf(v.y) << 16);
    pk.y = (unsigned)f2bf(v.z) | ((unsigned)f2bf(v.w) << 16);
    const int byte = row * 128 + ((((col >> 3) ^ (row & 7)) << 4)) + ((col >> 2) & 1) * 8;
    *reinterpret_cast<uint2*>(lds + byte) = pk;
  }
  if (tid < ROWS) {
    const float4* rp = reinterpret_cast<const float4*>(g + tid * DIM);
    float s = 0.f;
    #pragma unroll
    for (int j = 0; j < 16; ++j) {
      const float4 v = rp[j];
      s += v.x * v.x + v.y * v.y + v.z * v.z + v.w * v.w;
    }
    sq[tid] = s;
  }
}

// Load one 16x32 MFMA operand fragment (8 bf16 per lane) from swizzled LDS.
__device__ __forceinline__ bf16x8 frag_load(const char* lds, int row, int ks, int lane) {
  return *reinterpret_cast<const bf16x8*>(
      lds + row * 128 + (((ks * 4 + (lane >> 4)) ^ (row & 7)) << 4));
}

// Kernel 1: partial row sums of exp(-sqrt(max(q2+k2-2qk,0))/8).
// Swapped MFMA (mfma(K,Q)): acc[i] = S[qrow=w*16+(lane&15)][kcol=c*16+(lane>>4)*4+i]
// grid (4 colsplit, NQ/64, BATCH), block 256. Scores <= 0 so no max-subtraction.
__global__ __launch_bounds__(256) void k_rowsum(
    const float* __restrict__ Qg, const float* __restrict__ Kg,
    float* __restrict__ partials) {
  __shared__ char Qlds[64 * 128];
  __shared__ char Klds[256 * 128];
  __shared__ float q2[64];
  __shared__ float k2[256];
  const int tid = threadIdx.x;
  const int cs = blockIdx.x;
  const int brow = blockIdx.y * 64;
  const int b = blockIdx.z;
  const float* Qb = Qg + ((size_t)b * NQ + brow) * DIM;
  const float* Kb = Kg + (size_t)b * NK * DIM;

  stage_tile<64>(Qb, Qlds, q2, tid);
  __syncthreads();

  const int lane = tid & 63, w = tid >> 6;
  const int qrow = w * 16 + (lane & 15);
  const bf16x8 qf0 = frag_load(Qlds, qrow, 0, lane);
  const bf16x8 qf1 = frag_load(Qlds, qrow, 1, lane);
  const float q2r = q2[qrow];
  const int g = lane >> 4;

  float rowsum = 0.f;
  for (int t = 0; t < 4; ++t) {
    __syncthreads();  // previous tile's reads complete before overwrite
    stage_tile<256>(Kb + ((size_t)(cs * 4 + t)) * 256 * DIM, Klds, k2, tid);
    __syncthreads();
    #pragma unroll
    for (int c = 0; c < 16; ++c) {
      const int krow = c * 16 + (lane & 15);
      const bf16x8 kf0 = frag_load(Klds, krow, 0, lane);
      const bf16x8 kf1 = frag_load(Klds, krow, 1, lane);
      f32x4 acc = {0.f, 0.f, 0.f, 0.f};
      acc = __builtin_amdgcn_mfma_f32_16x16x32_bf16(kf0, qf0, acc, 0, 0, 0);
      acc = __builtin_amdgcn_mfma_f32_16x16x32_bf16(kf1, qf1, acc, 0, 0, 0);
      const float4 k2v = *reinterpret_cast<const float4*>(k2 + c * 16 + g * 4);
      const float k2a[4] = {k2v.x, k2v.y, k2v.z, k2v.w};
      #pragma unroll
      for (int i = 0; i < 4; ++i) {
        const float d2 = fmaxf(q2r + k2a[i] - 2.f * acc[i], 0.f);
        rowsum += __expf(-0.125f * sqrtf(d2));
      }
    }
  }
  // lanes {l, l^16, l^32, l^48} share a q-row -> reduce over lane bits 4,5
  rowsum += __shfl_xor(rowsum, 16, 64);
  rowsum += __shfl_xor(rowsum, 32, 64);
  if (lane < 16)
    partials[((size_t)cs * BATCH + b) * NQ + brow + w * 16 + lane] = rowsum;
}

// Collapse 4 partials per row -> inv = 1/rowsum.  grid 64 x 256.
__global__ __launch_bounds__(256) void k_inv(
    const float* __restrict__ partials, float* __restrict__ inv) {
  const int idx = blockIdx.x * 256 + threadIdx.x;  // b*NQ + row
  float s = 0.f;
  #pragma unroll
  for (int p = 0; p < 4; ++p) s += partials[(size_t)p * (BATCH * NQ) + idx];
  inv[idx] = 1.f / s;
}

// Kernel 3: recompute scores, write exp(s)*inv[row] as ONE float4 per c-iter.
// grid (NK/256, NQ/64, BATCH), block 256. Out written exactly once.
__global__ __launch_bounds__(256) void k_write(
    const float* __restrict__ Qg, const float* __restrict__ Kg,
    const float* __restrict__ inv, float* __restrict__ out) {
  __shared__ char Qlds[64 * 128];
  __shared__ char Klds[256 * 128];
  __shared__ float q2[64];
  __shared__ float k2[256];
  const int tid = threadIdx.x;
  const int bcol = blockIdx.x * 256;
  const int brow = blockIdx.y * 64;
  const int b = blockIdx.z;
  const float* Qb = Qg + ((size_t)b * NQ + brow) * DIM;
  const float* Kb = Kg + ((size_t)b * NK + bcol) * DIM;

  stage_tile<64>(Qb, Qlds, q2, tid);
  stage_tile<256>(Kb, Klds, k2, tid);
  __syncthreads();

  const int lane = tid & 63, w = tid >> 6;
  const int qrow = w * 16 + (lane & 15);
  const bf16x8 qf0 = frag_load(Qlds, qrow, 0, lane);
  const bf16x8 qf1 = frag_load(Qlds, qrow, 1, lane);
  const float q2r = q2[qrow];
  const int g = lane >> 4;
  const float iv = inv[(size_t)b * NQ + brow + qrow];
  float* const obase = out + ((size_t)b * NQ + brow + qrow) * NK + bcol + g * 4;

  #pragma unroll
  for (int c = 0; c < 16; ++c) {
    const int krow = c * 16 + (lane & 15);
    const bf16x8 kf0 = frag_load(Klds, krow, 0, lane);
    const bf16x8 kf1 = frag_load(Klds, krow, 1, lane);
    f32x4 acc = {0.f, 0.f, 0.f, 0.f};
    acc = __builtin_amdgcn_mfma_f32_16x16x32_bf16(kf0, qf0, acc, 0, 0, 0);
    acc = __builtin_amdgcn_mfma_f32_16x16x32_bf16(kf1, qf1, acc, 0, 0, 0);
    const float4 k2v = *reinterpret_cast<const float4*>(k2 + c * 16 + g * 4);
    const float k2a[4] = {k2v.x, k2v.y, k2v.z, k2v.w};
    float4 st;
    float e[4];
    #pragma unroll
    for (int i = 0; i < 4; ++i) {
      const float d2 = fmaxf(q2r + k2a[i] - 2.f * acc[i], 0.f);
      e[i] = __expf(-0.125f * sqrtf(d2)) * iv;
    }
    st.x = e[0]; st.y = e[1]; st.z = e[2]; st.w = e[3];
    *reinterpret_cast<float4*>(obase + c * 16) = st;
  }
}

extern "C" void kernel_launch(void* const* d_in, const int* in_sizes, int n_in,
                              void* d_out, int out_size, void* d_ws, size_t ws_size,
                              hipStream_t stream) {
  const float* Q = (const float*)d_in[0];
  const float* K = (const float*)d_in[1];
  float* out = (float*)d_out;

  float* partials = (float*)d_ws;                               // 256 KB
  float* inv = (float*)((char*)d_ws + (size_t)4 * BATCH * NQ * 4);  // 64 KB

  k_rowsum<<<dim3(4, NQ / 64, BATCH), dim3(256), 0, stream>>>(Q, K, partials);
  k_inv<<<dim3(BATCH * NQ / 256), dim3(256), 0, stream>>>(partials, inv);
  k_write<<<dim3(NK / 256, NQ / 64, BATCH), dim3(256), 0, stream>>>(Q, K, inv, out);
}